// Round 10
// baseline (2330.532 us; speedup 1.0000x reference)
//
#include <hip/hip_runtime.h>
#include <hip/hip_bf16.h>
#include <stdint.h>

#define BATCH 64
#define SEQ   512
#define INDIM 1024
#define HDIM  1024
#define NBLK  128
#define NPAIR 4      // 4 pair-groups x 16 batch rows
#define PSLOT 32     // blocks per pair, 32 hidden cols each
#define DEPTH 4      // h ring depth
#define FPAD  16     // 64 B per flag
#define PBUF_U16 32768   // u16 per (pair, depth) buffer: 32 k32 * 64 * 16

typedef short bf16x8 __attribute__((ext_vector_type(8)));
typedef short s16x4  __attribute__((ext_vector_type(4)));
typedef float f32x4  __attribute__((ext_vector_type(4)));
typedef unsigned short u16;
typedef unsigned int   u32;
typedef u32 u32x4 __attribute__((ext_vector_type(4)));
typedef u16 u16x4 __attribute__((ext_vector_type(4)));

static __device__ __forceinline__ u16 f2bf(float x) {
  unsigned int u = __float_as_uint(x);
  u += 0x7fffu + ((u >> 16) & 1u);
  return (u16)(u >> 16);
}
static __device__ __forceinline__ float bf2f(u16 b) {
  return __uint_as_float(((unsigned int)b) << 16);
}

// device-coherent (LLC-scope) scalar load — proven sync primitive (r9)
static __device__ __forceinline__ int coh_ld_i32(const int* p) {
  int v;
  asm volatile("global_load_dword %0, %1, off sc0 sc1\n\t"
               "s_waitcnt vmcnt(0)"
               : "=&v"(v) : "v"(p) : "memory");
  return v;
}

static __device__ __forceinline__ void split4(float4 v, u16x4& hi, u16x4& lo) {
  hi.x = f2bf(v.x); lo.x = f2bf(v.x - bf2f(hi.x));
  hi.y = f2bf(v.y); lo.y = f2bf(v.y - bf2f(hi.y));
  hi.z = f2bf(v.z); lo.z = f2bf(v.z - bf2f(hi.z));
  hi.w = f2bf(v.w); lo.w = f2bf(v.w - bf2f(hi.w));
}
static __device__ __forceinline__ bf16x8 ld8(const u16* p) {
  s16x4 a = *(const s16x4*)p;
  s16x4 b = *(const s16x4*)(p + 4);
  return __builtin_shufflevector(a, b, 0, 1, 2, 3, 4, 5, 6, 7);
}

// ---- init0: poison h ring (0xFFFFFFFF = tag-1 everywhere), zero flags ----
__global__ void init0(u32* __restrict__ ws) {
  int i = blockIdx.x * blockDim.x + threadIdx.x;
  const int hdw = NPAIR * DEPTH * (PBUF_U16 / 2);   // 262144 dwords
  if (i < hdw) ws[i] = 0xFFFFFFFFu;
  else if (i < hdw + NPAIR * PSLOT * FPAD) ws[i] = 0;
}

// ---- init1: pack h0 into buf0 of each pair, interleaved (hi|lo<<16), tag 0 ----
// pair pp = rows [16pp,16pp+16). dword index (k32*64 + kg*16 + r)*8 + j holds
// h[16pp + r][k32*32 + kg*8 + j].
__global__ void init1(const float* __restrict__ h0, u32* __restrict__ hw) {
  int i = blockIdx.x * blockDim.x + threadIdx.x;
  if (i < BATCH * HDIM) {
    int b = i >> 10, k = i & 1023;
    int pp = b >> 4, r = b & 15;
    int k32 = k >> 5, kg = (k >> 3) & 3, j = k & 7;
    float x = h0[i];
    u16 hi = f2bf(x);
    u16 lo = f2bf(x - bf2f(hi));
    size_t di = (size_t)pp * (DEPTH * PBUF_U16 / 2) + (size_t)((k32 * 64 + kg * 16 + r) * 8 + j);
    hw[di] = (u32)hi | ((u32)lo << 16);
  }
}

// ---- xproj: xp = X @ Wih^T + bih + bhh via split-bf16 MFMA (into out) ----
__global__ __launch_bounds__(256) void xproj_kernel(const float* __restrict__ A,
                                                    const float* __restrict__ W,
                                                    const float* __restrict__ bih,
                                                    const float* __restrict__ bhh,
                                                    float* __restrict__ C) {
  __shared__ u16 Ah[4][128][12], Al[4][128][12], Bh[4][128][12], Bl[4][128][12];
  const int nb = blockIdx.x;
  const int mb = blockIdx.y;
  const int m_base = mb * 128, n_base = nb * 128;
  const int tid = (int)threadIdx.x;
  const int wid = tid >> 6, lane = tid & 63;
  const int wm = wid >> 1, wn = wid & 1;
  const int r = lane & 15, kg = lane >> 4;
  const int srow = tid >> 1;
  const int skq  = (tid & 1) * 16;

  const float* ap0 = A + (size_t)(m_base + srow) * INDIM + skq;
  const float* bp0 = W + (size_t)(n_base + srow) * INDIM + skq;

  f32x4 acc[4][4] = {};

  for (int k0 = 0; k0 < INDIM; k0 += 32) {
    float4 av[4], bv[4];
#pragma unroll
    for (int i = 0; i < 4; ++i) {
      av[i] = *(const float4*)(ap0 + k0 + i * 4);
      bv[i] = *(const float4*)(bp0 + k0 + i * 4);
    }
    __syncthreads();
#pragma unroll
    for (int i = 0; i < 4; ++i) {
      int kk = skq + i * 4;
      int kgw = kk >> 3, off = kk & 7;
      u16x4 hi, lo;
      split4(av[i], hi, lo);
      *(u16x4*)&Ah[kgw][srow][off] = hi;
      *(u16x4*)&Al[kgw][srow][off] = lo;
      split4(bv[i], hi, lo);
      *(u16x4*)&Bh[kgw][srow][off] = hi;
      *(u16x4*)&Bl[kgw][srow][off] = lo;
    }
    __syncthreads();

    bf16x8 ah[4], al[4], bhv[4], blv[4];
#pragma unroll
    for (int mf = 0; mf < 4; ++mf) {
      int row = wm * 64 + mf * 16 + r;
      ah[mf] = ld8(&Ah[kg][row][0]);
      al[mf] = ld8(&Al[kg][row][0]);
    }
#pragma unroll
    for (int nf = 0; nf < 4; ++nf) {
      int row = wn * 64 + nf * 16 + r;
      bhv[nf] = ld8(&Bh[kg][row][0]);
      blv[nf] = ld8(&Bl[kg][row][0]);
    }
#pragma unroll
    for (int mf = 0; mf < 4; ++mf)
#pragma unroll
      for (int nf = 0; nf < 4; ++nf) {
        acc[mf][nf] = __builtin_amdgcn_mfma_f32_16x16x32_bf16(ah[mf], bhv[nf], acc[mf][nf], 0, 0, 0);
        acc[mf][nf] = __builtin_amdgcn_mfma_f32_16x16x32_bf16(ah[mf], blv[nf], acc[mf][nf], 0, 0, 0);
        acc[mf][nf] = __builtin_amdgcn_mfma_f32_16x16x32_bf16(al[mf], bhv[nf], acc[mf][nf], 0, 0, 0);
      }
  }

#pragma unroll
  for (int nf = 0; nf < 4; ++nf) {
    int col = n_base + wn * 64 + nf * 16 + r;
    float bias = bih[col] + bhh[col];
#pragma unroll
    for (int mf = 0; mf < 4; ++mf) {
      int rowb = m_base + wm * 64 + mf * 16 + kg * 4;
#pragma unroll
      for (int q = 0; q < 4; ++q) {
        C[(size_t)(rowb + q) * HDIM + col] = acc[mf][nf][q] + bias;
      }
    }
  }
}

// ---- scan: persistent, tag-validated data-poll (no flag on read path) ----
// Block b: pp = b&3 (16 batch rows, two 8-row groups), slot = b>>2 (32 cols).
// MFMA tile rows 0-7 = rows 16pp+0..7, rows 8-15 = rows 16pp+8..15.
// Wave wv handles K in [wv*128, wv*128+128); epilogue = waves 0 (rows 0-7) and
// 1 (rows 8-15). Depth-4 h ring; epoch tag = ((t)>>2)&1 in bf16-hi sign bits.
__global__ __launch_bounds__(512, 1) void rnn_scan(
    const float* __restrict__ Whh, float* __restrict__ out,
    u16* hbase, int* flags) {
  __shared__ u16 WH[32][2][64][8], WL[32][2][64][8];   // 128 KB
  __shared__ float red[2][8][2][16][16];               // 32 KB (exactly fits 160K)

  const int blk = (int)blockIdx.x;
  const int pp = blk & 3;
  const int slot = blk >> 2;
  const int n0 = slot * 32;
  const int tid = (int)threadIdx.x;
  const int wv = tid >> 6, lane = tid & 63;
  const int r = lane & 15, kg = lane >> 4;

  // ---- one-time: stage Whh rows n0..n0+31 into LDS, fragment-major, hi/lo ----
  for (int it = 0; it < 16; ++it) {
    int f4 = it * 512 + tid;
    int row = f4 >> 8;                  // 0..31
    int k0 = (f4 & 255) * 4;
    float4 v = *(const float4*)(Whh + (size_t)(n0 + row) * HDIM + k0);
    int k32 = k0 >> 5, kgg = (k0 >> 3) & 3, j = k0 & 7;
    int nt = row >> 4, ln = kgg * 16 + (row & 15);
    u16x4 hi, lo;
    split4(v, hi, lo);
    *(u16x4*)&WH[k32][nt][ln][j] = hi;
    *(u16x4*)&WL[k32][nt][ln][j] = lo;
  }
  __syncthreads();

  u16* const hpair = hbase + (size_t)pp * (DEPTH * PBUF_U16);
  int* const pflag = flags + pp * PSLOT * FPAD;

  // epilogue geometry (waves 0/1): tile row 0..15, col-quad ec 0..7
  const int erow = (wv == 1 ? 8 : 0) + (lane >> 3);
  const int ec = lane & 7;
  const float* xp0 = out + ((size_t)(pp * 16 + erow) * SEQ) * HDIM + n0 + ec * 4;
  float4 xf;
  if (wv < 2) xf = *(const float4*)xp0;   // xp(t=0)

  for (int t = 0; t < SEQ; ++t) {
    const int p2 = t & 1;
    const int rt = (t >> 2) & 1;                 // expected tag of h(t)
    const u32 rm = rt ? 0x80008000u : 0u;
    const u16 wm16 = (u16)((((t + 1) >> 2) & 1) << 15);  // tag for h(t+1)
    const u16* hc = hpair + (size_t)(t & 3) * PBUF_U16;
    u16* hn = hpair + (size_t)((t + 1) & 3) * PBUF_U16;

    // (a) data-poll: load this wave's 8 x dwordx4, validate tag bits
    u32x4 P0, P1, P2, P3, P4, P5, P6, P7;
    {
      const char* a0 = (const char*)hc + (size_t)((wv * 4) * 64 + lane) * 32;
      const char* a1 = a0 + 4096;
      for (;;) {
        asm volatile(
            "global_load_dwordx4 %0, %8, off sc0 sc1\n\t"
            "global_load_dwordx4 %1, %8, off offset:16 sc0 sc1\n\t"
            "global_load_dwordx4 %2, %8, off offset:2048 sc0 sc1\n\t"
            "global_load_dwordx4 %3, %8, off offset:2064 sc0 sc1\n\t"
            "global_load_dwordx4 %4, %9, off sc0 sc1\n\t"
            "global_load_dwordx4 %5, %9, off offset:16 sc0 sc1\n\t"
            "global_load_dwordx4 %6, %9, off offset:2048 sc0 sc1\n\t"
            "global_load_dwordx4 %7, %9, off offset:2064 sc0 sc1"
            : "=&v"(P0), "=&v"(P1), "=&v"(P2), "=&v"(P3),
              "=&v"(P4), "=&v"(P5), "=&v"(P6), "=&v"(P7)
            : "v"(a0), "v"(a1)
            : "memory");
        asm volatile("s_waitcnt vmcnt(0)"
            : "+v"(P0), "+v"(P1), "+v"(P2), "+v"(P3),
              "+v"(P4), "+v"(P5), "+v"(P6), "+v"(P7));
        if (t == 0) break;   // init-written, race-free
        bool okl;
        if (rt) {
          u32 m = P0[0] & P0[1] & P0[2] & P0[3] & P1[0] & P1[1] & P1[2] & P1[3]
                & P2[0] & P2[1] & P2[2] & P2[3] & P3[0] & P3[1] & P3[2] & P3[3]
                & P4[0] & P4[1] & P4[2] & P4[3] & P5[0] & P5[1] & P5[2] & P5[3]
                & P6[0] & P6[1] & P6[2] & P6[3] & P7[0] & P7[1] & P7[2] & P7[3];
          okl = ((m >> 15) & 1u) != 0;
        } else {
          u32 m = P0[0] | P0[1] | P0[2] | P0[3] | P1[0] | P1[1] | P1[2] | P1[3]
                | P2[0] | P2[1] | P2[2] | P2[3] | P3[0] | P3[1] | P3[2] | P3[3]
                | P4[0] | P4[1] | P4[2] | P4[3] | P5[0] | P5[1] | P5[2] | P5[3]
                | P6[0] | P6[1] | P6[2] | P6[3] | P7[0] | P7[1] | P7[2] | P7[3];
          okl = ((m >> 15) & 1u) == 0;
        }
        if (__all((int)okl)) break;
      }
    }

    // (a2) early-issue write-safety flag gather (drained by the barrier)
    int fv = 0;
    if (wv < 2 && t >= 3) {
      const int* fp = pflag + (lane & 31) * FPAD;
      asm volatile("global_load_dword %0, %1, off sc0 sc1"
                   : "=v"(fv) : "v"(fp) : "memory");
    }

    // (b) unpack + MFMA (6 per k32: h-hi*W-hi, h-hi*W-lo, h-lo*W-hi per ntile)
    f32x4 acc0 = {0.f, 0.f, 0.f, 0.f};
    f32x4 acc1 = {0.f, 0.f, 0.f, 0.f};
#define DO_K32(i, QA, QB)                                                      \
    {                                                                          \
      u32 d0 = QA[0], d1 = QA[1], d2 = QA[2], d3 = QA[3];                      \
      u32 d4 = QB[0], d5 = QB[1], d6 = QB[2], d7 = QB[3];                      \
      union { u32 w[4]; bf16x8 v; } AH, AL;                                    \
      AH.w[0] = ((d0 & 0xFFFFu) | (d1 << 16)) ^ rm;                            \
      AH.w[1] = ((d2 & 0xFFFFu) | (d3 << 16)) ^ rm;                            \
      AH.w[2] = ((d4 & 0xFFFFu) | (d5 << 16)) ^ rm;                            \
      AH.w[3] = ((d6 & 0xFFFFu) | (d7 << 16)) ^ rm;                            \
      AL.w[0] = (d0 >> 16) | (d1 & 0xFFFF0000u);                               \
      AL.w[1] = (d2 >> 16) | (d3 & 0xFFFF0000u);                               \
      AL.w[2] = (d4 >> 16) | (d5 & 0xFFFF0000u);                               \
      AL.w[3] = (d6 >> 16) | (d7 & 0xFFFF0000u);                               \
      int k32 = wv * 4 + (i);                                                  \
      bf16x8 b0h = *(const bf16x8*)&WH[k32][0][lane][0];                       \
      bf16x8 b0l = *(const bf16x8*)&WL[k32][0][lane][0];                       \
      bf16x8 b1h = *(const bf16x8*)&WH[k32][1][lane][0];                       \
      bf16x8 b1l = *(const bf16x8*)&WL[k32][1][lane][0];                       \
      acc0 = __builtin_amdgcn_mfma_f32_16x16x32_bf16(AH.v, b0h, acc0, 0, 0, 0);\
      acc0 = __builtin_amdgcn_mfma_f32_16x16x32_bf16(AH.v, b0l, acc0, 0, 0, 0);\
      acc0 = __builtin_amdgcn_mfma_f32_16x16x32_bf16(AL.v, b0h, acc0, 0, 0, 0);\
      acc1 = __builtin_amdgcn_mfma_f32_16x16x32_bf16(AH.v, b1h, acc1, 0, 0, 0);\
      acc1 = __builtin_amdgcn_mfma_f32_16x16x32_bf16(AH.v, b1l, acc1, 0, 0, 0);\
      acc1 = __builtin_amdgcn_mfma_f32_16x16x32_bf16(AL.v, b1h, acc1, 0, 0, 0);\
    }
    DO_K32(0, P0, P1)
    DO_K32(1, P2, P3)
    DO_K32(2, P4, P5)
    DO_K32(3, P6, P7)
#undef DO_K32

    // (c) K-reduction scratch. D: row = kg*4+q (tile row), col = r
#pragma unroll
    for (int q = 0; q < 4; ++q) {
      red[p2][wv][0][kg * 4 + q][r] = acc0[q];
      red[p2][wv][1][kg * 4 + q][r] = acc1[q];
    }
    __syncthreads();   // one barrier per step (drains flag gather too)

    if (wv < 2) {
      // own flag: reads of step t complete (post-barrier)
      if (wv == 0 && lane == 0) {
        int* fp = pflag + slot * FPAD;
        int tv = t + 1;
        asm volatile("global_store_dword %0, %1, off sc0 sc1"
                     :: "v"(fp), "v"(tv) : "memory");
      }
      // (d) reduce 8 waves + xp, relu
      f32x4 s = {xf.x, xf.y, xf.z, xf.w};
      int nt = ec >> 2, cl = (ec & 3) * 4;
#pragma unroll
      for (int w = 0; w < 8; ++w) s += *(const f32x4*)&red[p2][w][nt][erow][cl];
#pragma unroll
      for (int j = 0; j < 4; ++j) s[j] = s[j] > 0.f ? s[j] : 0.f;

      // write-safety: ring slot last read at t-3; need all flags >= t-2
      if (t >= 3) {
        asm volatile("s_waitcnt vmcnt(0)" : "+v"(fv));
        while (!__all(fv >= t - 2)) fv = coh_ld_i32(pflag + (lane & 31) * FPAD);
      }

      // pack tagged interleaved dwords, single 16B store (fire-and-forget)
      u32 dw0, dw1, dw2, dw3;
      {
        u16 h0 = f2bf(s[0]), h1 = f2bf(s[1]), h2 = f2bf(s[2]), h3 = f2bf(s[3]);
        u16 l0 = f2bf(s[0] - bf2f(h0)), l1 = f2bf(s[1] - bf2f(h1));
        u16 l2 = f2bf(s[2] - bf2f(h2)), l3 = f2bf(s[3] - bf2f(h3));
        dw0 = (u32)(u16)(h0 ^ wm16) | ((u32)l0 << 16);
        dw1 = (u32)(u16)(h1 ^ wm16) | ((u32)l1 << 16);
        dw2 = (u32)(u16)(h2 ^ wm16) | ((u32)l2 << 16);
        dw3 = (u32)(u16)(h3 ^ wm16) | ((u32)l3 << 16);
      }
      u32x4 D = {dw0, dw1, dw2, dw3};
      char* hp = (char*)hn + (size_t)((slot * 64 + (ec >> 1) * 16 + erow) * 32) + (ec & 1) * 16;
      asm volatile("global_store_dwordx4 %0, %1, off sc0 sc1"
                   :: "v"(hp), "v"(D) : "memory");

      // outputs + xp prefetch
      __builtin_nontemporal_store(s,
          (f32x4*)(out + ((size_t)(pp * 16 + erow) * SEQ + t) * HDIM + n0 + ec * 4));
      if (t + 1 < SEQ) xf = *(const float4*)(xp0 + (size_t)(t + 1) * HDIM);
    }
  }
}

// ---- h_n = outputs[:, SEQ-1, :] ----
__global__ void copy_hn(const float* __restrict__ out, float* __restrict__ hn) {
  int idx = blockIdx.x * blockDim.x + threadIdx.x;
  if (idx < BATCH * HDIM) {
    int b = idx >> 10, j = idx & 1023;
    hn[idx] = out[((size_t)b * SEQ + (SEQ - 1)) * (size_t)HDIM + j];
  }
}

extern "C" void kernel_launch(void* const* d_in, const int* in_sizes, int n_in,
                              void* d_out, int out_size, void* d_ws, size_t ws_size,
                              hipStream_t stream) {
  const float* inputs = (const float*)d_in[0];
  const float* h0     = (const float*)d_in[1];
  const float* w_ih   = (const float*)d_in[2];
  const float* w_hh   = (const float*)d_in[3];
  const float* b_ih   = (const float*)d_in[4];
  const float* b_hh   = (const float*)d_in[5];

  float* outBase = (float*)d_out;
  float* hnBase  = outBase + (size_t)BATCH * SEQ * HDIM;

  // ws: h ring (4 pairs x 4 bufs x 64 KB = 1 MB) | flags 8 KB
  u16* hbase = (u16*)d_ws;
  int* flags = (int*)(hbase + (size_t)NPAIR * DEPTH * PBUF_U16);

  const int init_n = NPAIR * DEPTH * (PBUF_U16 / 2) + NPAIR * PSLOT * FPAD;
  init0<<<(init_n + 255) / 256, 256, 0, stream>>>((u32*)d_ws);
  init1<<<(BATCH * HDIM + 255) / 256, 256, 0, stream>>>(h0, (u32*)hbase);

  xproj_kernel<<<dim3(8, 256), 256, 0, stream>>>(inputs, w_ih, b_ih, b_hh, outBase);

  const float* wha = w_hh;
  float* oa = outBase;
  u16* hba = hbase;
  int* fa = flags;
  void* args[4] = {&wha, &oa, &hba, &fa};
  (void)hipLaunchCooperativeKernel((const void*)rnn_scan, dim3(NBLK), dim3(512), args, 0, stream);

  copy_hn<<<256, 256, 0, stream>>>(outBase, hnBase);
}

// Round 11
// 2264.888 us; speedup vs baseline: 1.0290x; 1.0290x over previous
//
#include <hip/hip_runtime.h>
#include <hip/hip_bf16.h>
#include <stdint.h>

#define BATCH 64
#define SEQ   512
#define INDIM 1024
#define HDIM  1024
#define NBLK  256
#define NGRP  8      // 8 groups x 8 batch rows
#define GSLOT 32     // blocks per group, 32 hidden cols each
#define DEPTH 4      // h ring depth
#define FPAD  16     // 64 B per flag
#define GBUF_U16 32768   // u16 per (group, depth): 32 k32 * 64 slots * 16
#define GBUF_DW  16384

typedef short bf16x8 __attribute__((ext_vector_type(8)));
typedef short s16x4  __attribute__((ext_vector_type(4)));
typedef float f32x2  __attribute__((ext_vector_type(2)));
typedef float f32x4  __attribute__((ext_vector_type(4)));
typedef unsigned short u16;
typedef unsigned int   u32;
typedef u32 u32x2 __attribute__((ext_vector_type(2)));
typedef u32 u32x4 __attribute__((ext_vector_type(4)));
typedef u16 u16x4 __attribute__((ext_vector_type(4)));

static __device__ __forceinline__ u16 f2bf(float x) {
  unsigned int u = __float_as_uint(x);
  u += 0x7fffu + ((u >> 16) & 1u);
  return (u16)(u >> 16);
}
static __device__ __forceinline__ float bf2f(u16 b) {
  return __uint_as_float(((unsigned int)b) << 16);
}

// device-coherent (LLC-scope) scalar load — proven sync primitive (r9)
static __device__ __forceinline__ int coh_ld_i32(const int* p) {
  int v;
  asm volatile("global_load_dword %0, %1, off sc0 sc1\n\t"
               "s_waitcnt vmcnt(0)"
               : "=&v"(v) : "v"(p) : "memory");
  return v;
}

static __device__ __forceinline__ void split4(float4 v, u16x4& hi, u16x4& lo) {
  hi.x = f2bf(v.x); lo.x = f2bf(v.x - bf2f(hi.x));
  hi.y = f2bf(v.y); lo.y = f2bf(v.y - bf2f(hi.y));
  hi.z = f2bf(v.z); lo.z = f2bf(v.z - bf2f(hi.z));
  hi.w = f2bf(v.w); lo.w = f2bf(v.w - bf2f(hi.w));
}
static __device__ __forceinline__ bf16x8 ld8(const u16* p) {
  s16x4 a = *(const s16x4*)p;
  s16x4 b = *(const s16x4*)(p + 4);
  return __builtin_shufflevector(a, b, 0, 1, 2, 3, 4, 5, 6, 7);
}

// ---- init0: poison h ring (tag=1 everywhere), zero flags ----
__global__ void init0(u32* __restrict__ ws) {
  int i = blockIdx.x * blockDim.x + threadIdx.x;
  const int hdw = NGRP * DEPTH * GBUF_DW;   // 524288 dwords
  if (i < hdw) ws[i] = 0xFFFFFFFFu;
  else if (i < hdw + NGRP * GSLOT * FPAD) ws[i] = 0;
}

// ---- init1: pack h0 into buf0 of each group, interleaved (hi|lo<<16), natural sign ----
// group g = rows [8g, 8g+8). dword idx (k32*64 + kg*16 + r)*8 + j holds
// h[8g + r][k32*32 + kg*8 + j]. Rows r=8..15 remain poison (never read).
__global__ void init1(const float* __restrict__ h0, u32* __restrict__ hw) {
  int i = blockIdx.x * blockDim.x + threadIdx.x;
  if (i < BATCH * HDIM) {
    int b = i >> 10, k = i & 1023;
    int g = b >> 3, r = b & 7;
    int k32 = k >> 5, kg = (k >> 3) & 3, j = k & 7;
    float x = h0[i];
    u16 hi = f2bf(x);
    u16 lo = f2bf(x - bf2f(hi));
    size_t di = (size_t)g * (DEPTH * GBUF_DW) + (size_t)((k32 * 64 + kg * 16 + r) * 8 + j);
    hw[di] = (u32)hi | ((u32)lo << 16);
  }
}

// ---- xproj: xp = X @ Wih^T + bih + bhh via split-bf16 MFMA (into out) ----
__global__ __launch_bounds__(256) void xproj_kernel(const float* __restrict__ A,
                                                    const float* __restrict__ W,
                                                    const float* __restrict__ bih,
                                                    const float* __restrict__ bhh,
                                                    float* __restrict__ C) {
  __shared__ u16 Ah[4][128][12], Al[4][128][12], Bh[4][128][12], Bl[4][128][12];
  const int nb = blockIdx.x;
  const int mb = blockIdx.y;
  const int m_base = mb * 128, n_base = nb * 128;
  const int tid = (int)threadIdx.x;
  const int wid = tid >> 6, lane = tid & 63;
  const int wm = wid >> 1, wn = wid & 1;
  const int r = lane & 15, kg = lane >> 4;
  const int srow = tid >> 1;
  const int skq  = (tid & 1) * 16;

  const float* ap0 = A + (size_t)(m_base + srow) * INDIM + skq;
  const float* bp0 = W + (size_t)(n_base + srow) * INDIM + skq;

  f32x4 acc[4][4] = {};

  for (int k0 = 0; k0 < INDIM; k0 += 32) {
    float4 av[4], bv[4];
#pragma unroll
    for (int i = 0; i < 4; ++i) {
      av[i] = *(const float4*)(ap0 + k0 + i * 4);
      bv[i] = *(const float4*)(bp0 + k0 + i * 4);
    }
    __syncthreads();
#pragma unroll
    for (int i = 0; i < 4; ++i) {
      int kk = skq + i * 4;
      int kgw = kk >> 3, off = kk & 7;
      u16x4 hi, lo;
      split4(av[i], hi, lo);
      *(u16x4*)&Ah[kgw][srow][off] = hi;
      *(u16x4*)&Al[kgw][srow][off] = lo;
      split4(bv[i], hi, lo);
      *(u16x4*)&Bh[kgw][srow][off] = hi;
      *(u16x4*)&Bl[kgw][srow][off] = lo;
    }
    __syncthreads();

    bf16x8 ah[4], al[4], bhv[4], blv[4];
#pragma unroll
    for (int mf = 0; mf < 4; ++mf) {
      int row = wm * 64 + mf * 16 + r;
      ah[mf] = ld8(&Ah[kg][row][0]);
      al[mf] = ld8(&Al[kg][row][0]);
    }
#pragma unroll
    for (int nf = 0; nf < 4; ++nf) {
      int row = wn * 64 + nf * 16 + r;
      bhv[nf] = ld8(&Bh[kg][row][0]);
      blv[nf] = ld8(&Bl[kg][row][0]);
    }
#pragma unroll
    for (int mf = 0; mf < 4; ++mf)
#pragma unroll
      for (int nf = 0; nf < 4; ++nf) {
        acc[mf][nf] = __builtin_amdgcn_mfma_f32_16x16x32_bf16(ah[mf], bhv[nf], acc[mf][nf], 0, 0, 0);
        acc[mf][nf] = __builtin_amdgcn_mfma_f32_16x16x32_bf16(ah[mf], blv[nf], acc[mf][nf], 0, 0, 0);
        acc[mf][nf] = __builtin_amdgcn_mfma_f32_16x16x32_bf16(al[mf], bhv[nf], acc[mf][nf], 0, 0, 0);
      }
  }

#pragma unroll
  for (int nf = 0; nf < 4; ++nf) {
    int col = n_base + wn * 64 + nf * 16 + r;
    float bias = bih[col] + bhh[col];
#pragma unroll
    for (int mf = 0; mf < 4; ++mf) {
      int rowb = m_base + wm * 64 + mf * 16 + kg * 4;
#pragma unroll
      for (int q = 0; q < 4; ++q) {
        C[(size_t)(rowb + q) * HDIM + col] = acc[mf][nf][q] + bias;
      }
    }
  }
}

// ---- scan: r9 geometry + tagged data exchange (no flag / no ack on read path).
// Block b: grp = b&7 (rows [8g,8g+8)), slot = b>>3 (cols [32s,32s+32)).
// Wave wv: K in [wv*128, +128). Depth-4 ring, tag = (t>>2)&1 in bf16-hi sign.
__global__ __launch_bounds__(512, 1) void rnn_scan(
    const float* __restrict__ Whh, float* __restrict__ out,
    u16* hbase, int* flags) {
  __shared__ u16 WH[32][2][64][8], WL[32][2][64][8];   // 128 KB
  __shared__ __align__(16) float red[2][8][2][8][20];  // 20 KB

  const int blk = (int)blockIdx.x;
  const int grp = blk & 7;
  const int slot = blk >> 3;
  const int n0 = slot * 32;
  const int tid = (int)threadIdx.x;
  const int wv = tid >> 6, lane = tid & 63;
  const int r = lane & 15, kg = lane >> 4;
  const bool zrow = r >= 8;

  // ---- one-time: stage Whh rows n0..n0+31 into LDS, fragment-major, hi/lo ----
  for (int it = 0; it < 16; ++it) {
    int f4 = it * 512 + tid;
    int row = f4 >> 8;                  // 0..31
    int k0 = (f4 & 255) * 4;
    float4 v = *(const float4*)(Whh + (size_t)(n0 + row) * HDIM + k0);
    int k32 = k0 >> 5, kgg = (k0 >> 3) & 3, j = k0 & 7;
    int nt = row >> 4, ln = kgg * 16 + (row & 15);
    u16x4 hi, lo;
    split4(v, hi, lo);
    *(u16x4*)&WH[k32][nt][ln][j] = hi;
    *(u16x4*)&WL[k32][nt][ln][j] = lo;
  }
  __syncthreads();

  u16* const hring = hbase + (size_t)grp * (DEPTH * GBUF_U16);
  int* const gflag = flags + grp * GSLOT * FPAD;

  // epilogue geometry (waves 0/1): eid -> (row 0..7, even col cc 0..30)
  const int eid = wv * 64 + lane;      // 0..127 for wv<2
  const int erow = (eid >> 4) & 7;
  const int ecc = (eid & 15) * 2;
  const float* xp0 = out + ((size_t)(grp * 8 + erow) * SEQ) * HDIM + n0 + ecc;
  f32x2 xf;
  if (wv < 2) xf = *(const f32x2*)xp0;   // xp(t=0)

  for (int t = 0; t < SEQ; ++t) {
    const int p2 = t & 1;
    const int rt = (t >> 2) & 1;                  // expected tag of h(t)
    const u32 rm = rt ? 0x80008000u : 0u;
    const u16 wtag = (u16)((((t + 1) >> 2) & 1) << 15);
    const u16* hc = hring + (size_t)(t & 3) * GBUF_U16;
    u16* hn = hring + (size_t)((t + 1) & 3) * GBUF_U16;

    // (a) tagged data poll: sentinel spin (16B, rotated over my 4 producers),
    //     then full 8x16B load + per-dword validation
    u32x4 P0, P1, P2, P3, P4, P5, P6, P7;
    if (!zrow) {
      const char* a0 = (const char*)hc + (size_t)((wv * 4) * 64 + lane) * 32;
      const char* a1 = a0 + 4096;
      if (t > 0) {
        const char* ap = (const char*)hc + (size_t)(((wv * 4 + (r & 3)) * 64) + lane) * 32;
        for (;;) {
          u32x4 S;
          asm volatile("global_load_dwordx4 %0, %1, off sc0 sc1\n\t"
                       "s_waitcnt vmcnt(0)"
                       : "=&v"(S) : "v"(ap) : "memory");
          u32 m = rt ? (S[0] & S[1] & S[2] & S[3]) : (S[0] | S[1] | S[2] | S[3]);
          bool ok = ((m >> 15) & 1u) == (u32)rt;
          if (__all((int)ok)) break;
        }
      }
      for (;;) {
        asm volatile(
            "global_load_dwordx4 %0, %8, off sc0 sc1\n\t"
            "global_load_dwordx4 %1, %8, off offset:16 sc0 sc1\n\t"
            "global_load_dwordx4 %2, %8, off offset:2048 sc0 sc1\n\t"
            "global_load_dwordx4 %3, %8, off offset:2064 sc0 sc1\n\t"
            "global_load_dwordx4 %4, %9, off sc0 sc1\n\t"
            "global_load_dwordx4 %5, %9, off offset:16 sc0 sc1\n\t"
            "global_load_dwordx4 %6, %9, off offset:2048 sc0 sc1\n\t"
            "global_load_dwordx4 %7, %9, off offset:2064 sc0 sc1"
            : "=&v"(P0), "=&v"(P1), "=&v"(P2), "=&v"(P3),
              "=&v"(P4), "=&v"(P5), "=&v"(P6), "=&v"(P7)
            : "v"(a0), "v"(a1)
            : "memory");
        asm volatile("s_waitcnt vmcnt(0)"
            : "+v"(P0), "+v"(P1), "+v"(P2), "+v"(P3),
              "+v"(P4), "+v"(P5), "+v"(P6), "+v"(P7));
        if (t == 0) break;
        u32 m;
        if (rt) {
          m = P0[0] & P0[1] & P0[2] & P0[3] & P1[0] & P1[1] & P1[2] & P1[3]
            & P2[0] & P2[1] & P2[2] & P2[3] & P3[0] & P3[1] & P3[2] & P3[3]
            & P4[0] & P4[1] & P4[2] & P4[3] & P5[0] & P5[1] & P5[2] & P5[3]
            & P6[0] & P6[1] & P6[2] & P6[3] & P7[0] & P7[1] & P7[2] & P7[3];
        } else {
          m = P0[0] | P0[1] | P0[2] | P0[3] | P1[0] | P1[1] | P1[2] | P1[3]
            | P2[0] | P2[1] | P2[2] | P2[3] | P3[0] | P3[1] | P3[2] | P3[3]
            | P4[0] | P4[1] | P4[2] | P4[3] | P5[0] | P5[1] | P5[2] | P5[3]
            | P6[0] | P6[1] | P6[2] | P6[3] | P7[0] | P7[1] | P7[2] | P7[3];
        }
        bool ok = ((m >> 15) & 1u) == (u32)rt;
        if (__all((int)ok)) break;
      }
    } else {
      P0 = P1 = P2 = P3 = P4 = P5 = P6 = P7 = (u32x4){0, 0, 0, 0};
    }

    // (a2) early-issue write-safety flag gather (drained by the barrier)
    int fv = 0;
    if (wv < 2 && t >= 3) {
      const int* fp = gflag + (lane & 31) * FPAD;
      asm volatile("global_load_dword %0, %1, off sc0 sc1"
                   : "=v"(fv) : "v"(fp) : "memory");
    }

    // (b) unpack + MFMA
    f32x4 acc0 = {0.f, 0.f, 0.f, 0.f};
    f32x4 acc1 = {0.f, 0.f, 0.f, 0.f};
#define DO_K32(i, QA, QB)                                                      \
    {                                                                          \
      u32 d0 = QA[0], d1 = QA[1], d2 = QA[2], d3 = QA[3];                      \
      u32 d4 = QB[0], d5 = QB[1], d6 = QB[2], d7 = QB[3];                      \
      union { u32 w[4]; bf16x8 v; } AH, AL;                                    \
      AH.w[0] = ((d0 & 0xFFFFu) | (d1 << 16)) ^ rm;                            \
      AH.w[1] = ((d2 & 0xFFFFu) | (d3 << 16)) ^ rm;                            \
      AH.w[2] = ((d4 & 0xFFFFu) | (d5 << 16)) ^ rm;                            \
      AH.w[3] = ((d6 & 0xFFFFu) | (d7 << 16)) ^ rm;                            \
      AL.w[0] = (d0 >> 16) | (d1 & 0xFFFF0000u);                               \
      AL.w[1] = (d2 >> 16) | (d3 & 0xFFFF0000u);                               \
      AL.w[2] = (d4 >> 16) | (d5 & 0xFFFF0000u);                               \
      AL.w[3] = (d6 >> 16) | (d7 & 0xFFFF0000u);                               \
      int k32 = wv * 4 + (i);                                                  \
      bf16x8 b0h = *(const bf16x8*)&WH[k32][0][lane][0];                       \
      bf16x8 b0l = *(const bf16x8*)&WL[k32][0][lane][0];                       \
      bf16x8 b1h = *(const bf16x8*)&WH[k32][1][lane][0];                       \
      bf16x8 b1l = *(const bf16x8*)&WL[k32][1][lane][0];                       \
      acc0 = __builtin_amdgcn_mfma_f32_16x16x32_bf16(AH.v, b0h, acc0, 0, 0, 0);\
      acc0 = __builtin_amdgcn_mfma_f32_16x16x32_bf16(AH.v, b0l, acc0, 0, 0, 0);\
      acc0 = __builtin_amdgcn_mfma_f32_16x16x32_bf16(AL.v, b0h, acc0, 0, 0, 0);\
      acc1 = __builtin_amdgcn_mfma_f32_16x16x32_bf16(AH.v, b1h, acc1, 0, 0, 0);\
      acc1 = __builtin_amdgcn_mfma_f32_16x16x32_bf16(AH.v, b1l, acc1, 0, 0, 0);\
      acc1 = __builtin_amdgcn_mfma_f32_16x16x32_bf16(AL.v, b1h, acc1, 0, 0, 0);\
    }
    DO_K32(0, P0, P1)
    DO_K32(1, P2, P3)
    DO_K32(2, P4, P5)
    DO_K32(3, P6, P7)
#undef DO_K32

    // (c) K-reduction scratch. D: col = lane&15, row = kg*4+q (rows<8 only)
    if (kg < 2) {
#pragma unroll
      for (int q = 0; q < 4; ++q) {
        red[p2][wv][0][kg * 4 + q][r] = acc0[q];
        red[p2][wv][1][kg * 4 + q][r] = acc1[q];
      }
    }
    __syncthreads();   // one barrier per step

    if (wv < 2) {
      // own flag: this block finished reading h(t) (post-barrier)
      if (wv == 0 && lane == 0) {
        int* fp = gflag + slot * FPAD;
        int tv = t + 1;
        asm volatile("global_store_dword %0, %1, off sc0 sc1"
                     :: "v"(fp), "v"(tv) : "memory");
      }
      // (d) reduce 8 waves + xp, relu (2 cols per lane)
      f32x2 s = xf;
      int nt = ecc >> 4, cl = ecc & 15;
#pragma unroll
      for (int w = 0; w < 8; ++w) {
        f32x2 v = *(const f32x2*)&red[p2][w][nt][erow][cl];
        s += v;
      }
      s.x = s.x > 0.f ? s.x : 0.f;
      s.y = s.y > 0.f ? s.y : 0.f;

      // write-safety: ring slot (t+1)&3 last read at t-3; need all flags >= t-2
      if (t >= 3) {
        asm volatile("s_waitcnt vmcnt(0)" : "+v"(fv));
        while (!__all(fv >= t - 2)) fv = coh_ld_i32(gflag + (lane & 31) * FPAD);
      }

      // pack 2 tagged dwords, fire-and-forget store
      u16 h0 = f2bf(s.x), h1 = f2bf(s.y);
      u16 l0 = f2bf(s.x - bf2f(h0)), l1 = f2bf(s.y - bf2f(h1));
      u32x2 D = {(u32)(u16)(h0 ^ wtag) | ((u32)l0 << 16),
                 (u32)(u16)(h1 ^ wtag) | ((u32)l1 << 16)};
      char* hp = (char*)hn + (size_t)((slot * 64 + (ecc >> 3) * 16 + erow) * 32) + (ecc & 7) * 4;
      asm volatile("global_store_dwordx2 %0, %1, off sc0 sc1"
                   :: "v"(hp), "v"(D) : "memory");

      // outputs + xp prefetch
      __builtin_nontemporal_store(s,
          (f32x2*)(out + ((size_t)(grp * 8 + erow) * SEQ + t) * HDIM + n0 + ecc));
      if (t + 1 < SEQ) xf = *(const f32x2*)(xp0 + (size_t)(t + 1) * HDIM);
    }
  }
}

// ---- h_n = outputs[:, SEQ-1, :] ----
__global__ void copy_hn(const float* __restrict__ out, float* __restrict__ hn) {
  int idx = blockIdx.x * blockDim.x + threadIdx.x;
  if (idx < BATCH * HDIM) {
    int b = idx >> 10, j = idx & 1023;
    hn[idx] = out[((size_t)b * SEQ + (SEQ - 1)) * (size_t)HDIM + j];
  }
}

extern "C" void kernel_launch(void* const* d_in, const int* in_sizes, int n_in,
                              void* d_out, int out_size, void* d_ws, size_t ws_size,
                              hipStream_t stream) {
  const float* inputs = (const float*)d_in[0];
  const float* h0     = (const float*)d_in[1];
  const float* w_ih   = (const float*)d_in[2];
  const float* w_hh   = (const float*)d_in[3];
  const float* b_ih   = (const float*)d_in[4];
  const float* b_hh   = (const float*)d_in[5];

  float* outBase = (float*)d_out;
  float* hnBase  = outBase + (size_t)BATCH * SEQ * HDIM;

  // ws: h ring (8 grp x 4 bufs x 64 KB = 2 MB) | flags 16 KB
  u16* hbase = (u16*)d_ws;
  int* flags = (int*)(hbase + (size_t)NGRP * DEPTH * GBUF_U16);

  const int init_n = NGRP * DEPTH * GBUF_DW + NGRP * GSLOT * FPAD;
  init0<<<(init_n + 255) / 256, 256, 0, stream>>>((u32*)d_ws);
  init1<<<(BATCH * HDIM + 255) / 256, 256, 0, stream>>>(h0, (u32*)hbase);

  xproj_kernel<<<dim3(8, 256), 256, 0, stream>>>(inputs, w_ih, b_ih, b_hh, outBase);

  const float* wha = w_hh;
  float* oa = outBase;
  u16* hba = hbase;
  int* fa = flags;
  void* args[4] = {&wha, &oa, &hba, &fa};
  (void)hipLaunchCooperativeKernel((const void*)rnn_scan, dim3(NBLK), dim3(512), args, 0, stream);

  copy_hn<<<256, 256, 0, stream>>>(outBase, hnBase);
}

// Round 12
// 1917.313 us; speedup vs baseline: 1.2155x; 1.1813x over previous
//
#include <hip/hip_runtime.h>
#include <hip/hip_bf16.h>
#include <stdint.h>

#define BATCH 64
#define SEQ   512
#define INDIM 1024
#define HDIM  1024
#define NBLK  256
#define NGRP  8      // 8 groups x 8 batch rows
#define GSLOT 32     // blocks per group, 32 hidden cols each
#define FPAD  16     // 64 B per flag
#define GBUF_U16 32768   // u16 per (group, buf): 32 k32 * 64 entries * 16
#define GBUF_DW  16384

typedef short bf16x8 __attribute__((ext_vector_type(8)));
typedef short s16x4  __attribute__((ext_vector_type(4)));
typedef float f32x4  __attribute__((ext_vector_type(4)));
typedef unsigned short u16;
typedef unsigned int   u32;
typedef u32 u32x4 __attribute__((ext_vector_type(4)));
typedef u16 u16x4 __attribute__((ext_vector_type(4)));

static __device__ __forceinline__ u16 f2bf(float x) {
  unsigned int u = __float_as_uint(x);
  u += 0x7fffu + ((u >> 16) & 1u);
  return (u16)(u >> 16);
}
static __device__ __forceinline__ float bf2f(u16 b) {
  return __uint_as_float(((unsigned int)b) << 16);
}

// device-coherent (system-scope) scalar load — proven flag-poll primitive (r9)
static __device__ __forceinline__ int coh_ld_i32(const int* p) {
  int v;
  asm volatile("global_load_dword %0, %1, off sc0 sc1\n\t"
               "s_waitcnt vmcnt(0)"
               : "=&v"(v) : "v"(p) : "memory");
  return v;
}

static __device__ __forceinline__ void split4(float4 v, u16x4& hi, u16x4& lo) {
  hi.x = f2bf(v.x); lo.x = f2bf(v.x - bf2f(hi.x));
  hi.y = f2bf(v.y); lo.y = f2bf(v.y - bf2f(hi.y));
  hi.z = f2bf(v.z); lo.z = f2bf(v.z - bf2f(hi.z));
  hi.w = f2bf(v.w); lo.w = f2bf(v.w - bf2f(hi.w));
}
static __device__ __forceinline__ bf16x8 ld8(const u16* p) {
  s16x4 a = *(const s16x4*)p;
  s16x4 b = *(const s16x4*)(p + 4);
  return __builtin_shufflevector(a, b, 0, 1, 2, 3, 4, 5, 6, 7);
}

// ---- init0: zero flags ----
__global__ void init0(int* __restrict__ flags, int n) {
  int i = blockIdx.x * blockDim.x + threadIdx.x;
  if (i < n) flags[i] = 0;
}

// ---- init1: pack h0 into buf0 of each group as interleaved dwords (hi|lo<<16) ----
// group g = rows [8g, 8g+8). dword idx (k32*64 + kg*16 + r)*8 + j holds
// h[8g + r][k32*32 + kg*8 + j]. Entries r=8..15 never read.
__global__ void init1(const float* __restrict__ h0, u32* __restrict__ hw) {
  int i = blockIdx.x * blockDim.x + threadIdx.x;
  if (i < BATCH * HDIM) {
    int b = i >> 10, k = i & 1023;
    int g = b >> 3, r = b & 7;
    int k32 = k >> 5, kg = (k >> 3) & 3, j = k & 7;
    float x = h0[i];
    u16 hi = f2bf(x);
    u16 lo = f2bf(x - bf2f(hi));
    size_t di = (size_t)g * (2 * GBUF_DW) + (size_t)((k32 * 64 + kg * 16 + r) * 8 + j);
    hw[di] = (u32)hi | ((u32)lo << 16);
  }
}

// ---- xproj: xp = X @ Wih^T + bih + bhh via split-bf16 MFMA (into out) ----
__global__ __launch_bounds__(256) void xproj_kernel(const float* __restrict__ A,
                                                    const float* __restrict__ W,
                                                    const float* __restrict__ bih,
                                                    const float* __restrict__ bhh,
                                                    float* __restrict__ C) {
  __shared__ u16 Ah[4][128][12], Al[4][128][12], Bh[4][128][12], Bl[4][128][12];
  const int nb = blockIdx.x;
  const int mb = blockIdx.y;
  const int m_base = mb * 128, n_base = nb * 128;
  const int tid = (int)threadIdx.x;
  const int wid = tid >> 6, lane = tid & 63;
  const int wm = wid >> 1, wn = wid & 1;
  const int r = lane & 15, kg = lane >> 4;
  const int srow = tid >> 1;
  const int skq  = (tid & 1) * 16;

  const float* ap0 = A + (size_t)(m_base + srow) * INDIM + skq;
  const float* bp0 = W + (size_t)(n_base + srow) * INDIM + skq;

  f32x4 acc[4][4] = {};

  for (int k0 = 0; k0 < INDIM; k0 += 32) {
    float4 av[4], bv[4];
#pragma unroll
    for (int i = 0; i < 4; ++i) {
      av[i] = *(const float4*)(ap0 + k0 + i * 4);
      bv[i] = *(const float4*)(bp0 + k0 + i * 4);
    }
    __syncthreads();
#pragma unroll
    for (int i = 0; i < 4; ++i) {
      int kk = skq + i * 4;
      int kgw = kk >> 3, off = kk & 7;
      u16x4 hi, lo;
      split4(av[i], hi, lo);
      *(u16x4*)&Ah[kgw][srow][off] = hi;
      *(u16x4*)&Al[kgw][srow][off] = lo;
      split4(bv[i], hi, lo);
      *(u16x4*)&Bh[kgw][srow][off] = hi;
      *(u16x4*)&Bl[kgw][srow][off] = lo;
    }
    __syncthreads();

    bf16x8 ah[4], al[4], bhv[4], blv[4];
#pragma unroll
    for (int mf = 0; mf < 4; ++mf) {
      int row = wm * 64 + mf * 16 + r;
      ah[mf] = ld8(&Ah[kg][row][0]);
      al[mf] = ld8(&Al[kg][row][0]);
    }
#pragma unroll
    for (int nf = 0; nf < 4; ++nf) {
      int row = wn * 64 + nf * 16 + r;
      bhv[nf] = ld8(&Bh[kg][row][0]);
      blv[nf] = ld8(&Bl[kg][row][0]);
    }
#pragma unroll
    for (int mf = 0; mf < 4; ++mf)
#pragma unroll
      for (int nf = 0; nf < 4; ++nf) {
        acc[mf][nf] = __builtin_amdgcn_mfma_f32_16x16x32_bf16(ah[mf], bhv[nf], acc[mf][nf], 0, 0, 0);
        acc[mf][nf] = __builtin_amdgcn_mfma_f32_16x16x32_bf16(ah[mf], blv[nf], acc[mf][nf], 0, 0, 0);
        acc[mf][nf] = __builtin_amdgcn_mfma_f32_16x16x32_bf16(al[mf], bhv[nf], acc[mf][nf], 0, 0, 0);
      }
  }

#pragma unroll
  for (int nf = 0; nf < 4; ++nf) {
    int col = n_base + wn * 64 + nf * 16 + r;
    float bias = bih[col] + bhh[col];
#pragma unroll
    for (int mf = 0; mf < 4; ++mf) {
      int rowb = m_base + wm * 64 + mf * 16 + kg * 4;
#pragma unroll
      for (int q = 0; q < 4; ++q) {
        C[(size_t)(rowb + q) * HDIM + col] = acc[mf][nf][q] + bias;
      }
    }
  }
}

// ---- scan: r9 structure + (sc1 h-stores, distributed 4-wave epilogue,
//      deferred out-store off the poll path). Depth-2 ring, flag-gated.
// Block b: grp = b&7 (rows [8g,8g+8)), slot = b>>3 (cols [32s,32s+32)).
// Wave wv: K in [wv*128, +128) -> consumes slabs (producers) 4wv..4wv+3.
// Producer epilogue = waves 0-3, 1 col/lane; sub-flag per epilogue wave.
__global__ __launch_bounds__(512, 1) void rnn_scan(
    const float* __restrict__ Whh, float* __restrict__ out,
    u16* hbase, int* flags) {
  __shared__ u16 WH[32][2][64][8], WL[32][2][64][8];   // 128 KB
  __shared__ __align__(16) float red[2][8][2][8][20];  // 20 KB

  const int blk = (int)blockIdx.x;
  const int grp = blk & 7;
  const int slot = blk >> 3;
  const int n0 = slot * 32;
  const int tid = (int)threadIdx.x;
  const int wv = tid >> 6, lane = tid & 63;
  const int r = lane & 15, kg = lane >> 4;
  const bool zrow = r >= 8;

  // ---- one-time: stage Whh rows n0..n0+31 into LDS, fragment-major, hi/lo ----
  for (int it = 0; it < 16; ++it) {
    int f4 = it * 512 + tid;
    int row = f4 >> 8;                  // 0..31
    int k0 = (f4 & 255) * 4;
    float4 v = *(const float4*)(Whh + (size_t)(n0 + row) * HDIM + k0);
    int k32 = k0 >> 5, kgg = (k0 >> 3) & 3, j = k0 & 7;
    int nt = row >> 4, ln = kgg * 16 + (row & 15);
    u16x4 hi, lo;
    split4(v, hi, lo);
    *(u16x4*)&WH[k32][nt][ln][j] = hi;
    *(u16x4*)&WL[k32][nt][ln][j] = lo;
  }
  __syncthreads();

  u16* const hb0 = hbase + (size_t)grp * (2 * GBUF_U16);
  u16* const hb1 = hb0 + GBUF_U16;
  int* const gflag = flags + grp * (GSLOT * 4) * FPAD;
  // consumer poll: 16 sub-flags (4 producers x 4 epilogue waves), 4 lanes each
  const int* const pollp = gflag + ((wv << 4) + (lane & 15)) * FPAD;

  // epilogue geometry (waves 0-3): 1 col/lane
  const int eid = wv * 64 + lane;       // 0..255 for wv<4
  const int er = (eid >> 5) & 7;        // row 0..7
  const int ec = eid & 31;              // col 0..31
  const float* xpbase = out + ((size_t)(grp * 8 + er) * SEQ) * HDIM + n0 + ec;
  float xfCur = 0.f, xfNext = 0.f, sPrev = 0.f;
  if (wv < 4) xfCur = xpbase[0];        // xp(t=0)

  for (int t = 0; t < SEQ; ++t) {
    const int p2 = t & 1;
    const u16* hc = (t & 1) ? hb1 : hb0;
    u16* hn = (t & 1) ? hb0 : hb1;

    // (a) flag poll: h(t) slabs 4wv..4wv+3 complete (all 4 sub-flags each)
    if (t > 0) {
      int v;
      do { v = coh_ld_i32(pollp); } while (!__all(v >= t));
    }

    // (b) h-load: 8 x 16B system-scope loads (zrow lanes synthesize zeros)
    u32x4 P0, P1, P2, P3, P4, P5, P6, P7;
    if (!zrow) {
      const char* a0 = (const char*)hc + (size_t)((wv * 4) * 64 + lane) * 32;
      const char* a1 = a0 + 4096;
      asm volatile(
          "global_load_dwordx4 %0, %8, off sc0 sc1\n\t"
          "global_load_dwordx4 %1, %8, off offset:16 sc0 sc1\n\t"
          "global_load_dwordx4 %2, %8, off offset:2048 sc0 sc1\n\t"
          "global_load_dwordx4 %3, %8, off offset:2064 sc0 sc1\n\t"
          "global_load_dwordx4 %4, %9, off sc0 sc1\n\t"
          "global_load_dwordx4 %5, %9, off offset:16 sc0 sc1\n\t"
          "global_load_dwordx4 %6, %9, off offset:2048 sc0 sc1\n\t"
          "global_load_dwordx4 %7, %9, off offset:2064 sc0 sc1"
          : "=&v"(P0), "=&v"(P1), "=&v"(P2), "=&v"(P3),
            "=&v"(P4), "=&v"(P5), "=&v"(P6), "=&v"(P7)
          : "v"(a0), "v"(a1)
          : "memory");
      asm volatile("s_waitcnt vmcnt(0)"
          : "+v"(P0), "+v"(P1), "+v"(P2), "+v"(P3),
            "+v"(P4), "+v"(P5), "+v"(P6), "+v"(P7));
    } else {
      P0 = P1 = P2 = P3 = P4 = P5 = P6 = P7 = (u32x4){0, 0, 0, 0};
    }

    // (b2) deferred out-store(t-1) + xp(t+1) prefetch — drains under MFMA,
    //      NOT under the next poll's vmcnt(0)
    if (wv < 4) {
      if (t > 0)
        __builtin_nontemporal_store(sPrev, (float*)(xpbase + (size_t)(t - 1) * HDIM));
      if (t + 1 < SEQ) xfNext = xpbase[(size_t)(t + 1) * HDIM];
    }

    // (c) unpack + MFMA
    f32x4 acc0 = {0.f, 0.f, 0.f, 0.f};
    f32x4 acc1 = {0.f, 0.f, 0.f, 0.f};
#define DO_K32(i, QA, QB)                                                      \
    {                                                                          \
      u32 d0 = QA[0], d1 = QA[1], d2 = QA[2], d3 = QA[3];                      \
      u32 d4 = QB[0], d5 = QB[1], d6 = QB[2], d7 = QB[3];                      \
      union { u32 w[4]; bf16x8 v; } AH, AL;                                    \
      AH.w[0] = (d0 & 0xFFFFu) | (d1 << 16);                                   \
      AH.w[1] = (d2 & 0xFFFFu) | (d3 << 16);                                   \
      AH.w[2] = (d4 & 0xFFFFu) | (d5 << 16);                                   \
      AH.w[3] = (d6 & 0xFFFFu) | (d7 << 16);                                   \
      AL.w[0] = (d0 >> 16) | (d1 & 0xFFFF0000u);                               \
      AL.w[1] = (d2 >> 16) | (d3 & 0xFFFF0000u);                               \
      AL.w[2] = (d4 >> 16) | (d5 & 0xFFFF0000u);                               \
      AL.w[3] = (d6 >> 16) | (d7 & 0xFFFF0000u);                               \
      int k32 = wv * 4 + (i);                                                  \
      bf16x8 b0h = *(const bf16x8*)&WH[k32][0][lane][0];                       \
      bf16x8 b0l = *(const bf16x8*)&WL[k32][0][lane][0];                       \
      bf16x8 b1h = *(const bf16x8*)&WH[k32][1][lane][0];                       \
      bf16x8 b1l = *(const bf16x8*)&WL[k32][1][lane][0];                       \
      acc0 = __builtin_amdgcn_mfma_f32_16x16x32_bf16(AH.v, b0h, acc0, 0, 0, 0);\
      acc0 = __builtin_amdgcn_mfma_f32_16x16x32_bf16(AH.v, b0l, acc0, 0, 0, 0);\
      acc0 = __builtin_amdgcn_mfma_f32_16x16x32_bf16(AL.v, b0h, acc0, 0, 0, 0);\
      acc1 = __builtin_amdgcn_mfma_f32_16x16x32_bf16(AH.v, b1h, acc1, 0, 0, 0);\
      acc1 = __builtin_amdgcn_mfma_f32_16x16x32_bf16(AH.v, b1l, acc1, 0, 0, 0);\
      acc1 = __builtin_amdgcn_mfma_f32_16x16x32_bf16(AL.v, b1h, acc1, 0, 0, 0);\
    }
    DO_K32(0, P0, P1)
    DO_K32(1, P2, P3)
    DO_K32(2, P4, P5)
    DO_K32(3, P6, P7)
#undef DO_K32

    // (d) K-reduction scratch. D: col = lane&15, row = kg*4+q (rows<8 only)
    if (kg < 2) {
#pragma unroll
      for (int q = 0; q < 4; ++q) {
        red[p2][wv][0][kg * 4 + q][r] = acc0[q];
        red[p2][wv][1][kg * 4 + q][r] = acc1[q];
      }
    }
    __syncthreads();   // one barrier per step

    // (e) distributed epilogue: waves 0-3, 1 col/lane
    if (wv < 4) {
      float s = xfCur;
#pragma unroll
      for (int w = 0; w < 8; ++w) s += red[p2][w][ec >> 4][er][ec & 15];
      s = s > 0.f ? s : 0.f;
      sPrev = s;
      u16 hi = f2bf(s);
      u16 lo = f2bf(s - bf2f(hi));
      u32 dw = (u32)hi | ((u32)lo << 16);
      u32* hp = (u32*)hn + (size_t)((slot * 64 + (ec >> 3) * 16 + er) * 8 + (ec & 7));
      // agent-scope (MALL) store + ack, then system-scope sub-flag
      asm volatile("global_store_dword %0, %1, off sc1\n\t"
                   "s_waitcnt vmcnt(0)"
                   :: "v"(hp), "v"(dw) : "memory");
      if (lane == 0) {
        int* fp = gflag + (slot * 4 + wv) * FPAD;
        int tv = t + 1;
        asm volatile("global_store_dword %0, %1, off sc0 sc1"
                     :: "v"(fp), "v"(tv) : "memory");
      }
      xfCur = xfNext;
    }
  }

  // tail: store out(SEQ-1)
  if (wv < 4)
    __builtin_nontemporal_store(sPrev, (float*)(xpbase + (size_t)(SEQ - 1) * HDIM));
}

// ---- h_n = outputs[:, SEQ-1, :] ----
__global__ void copy_hn(const float* __restrict__ out, float* __restrict__ hn) {
  int idx = blockIdx.x * blockDim.x + threadIdx.x;
  if (idx < BATCH * HDIM) {
    int b = idx >> 10, j = idx & 1023;
    hn[idx] = out[((size_t)b * SEQ + (SEQ - 1)) * (size_t)HDIM + j];
  }
}

extern "C" void kernel_launch(void* const* d_in, const int* in_sizes, int n_in,
                              void* d_out, int out_size, void* d_ws, size_t ws_size,
                              hipStream_t stream) {
  const float* inputs = (const float*)d_in[0];
  const float* h0     = (const float*)d_in[1];
  const float* w_ih   = (const float*)d_in[2];
  const float* w_hh   = (const float*)d_in[3];
  const float* b_ih   = (const float*)d_in[4];
  const float* b_hh   = (const float*)d_in[5];

  float* outBase = (float*)d_out;
  float* hnBase  = outBase + (size_t)BATCH * SEQ * HDIM;

  // ws: h ring (8 grp x 2 bufs x 64 KB = 1 MB) | flags 64 KB
  u16* hbase = (u16*)d_ws;
  int* flags = (int*)(hbase + (size_t)NGRP * 2 * GBUF_U16);
  const int nflags = NGRP * GSLOT * 4 * FPAD;

  init0<<<(nflags + 255) / 256, 256, 0, stream>>>(flags, nflags);
  init1<<<(BATCH * HDIM + 255) / 256, 256, 0, stream>>>(h0, (u32*)hbase);

  xproj_kernel<<<dim3(8, 256), 256, 0, stream>>>(inputs, w_ih, b_ih, b_hh, outBase);

  const float* wha = w_hh;
  float* oa = outBase;
  u16* hba = hbase;
  int* fa = flags;
  void* args[4] = {&wha, &oa, &hba, &fa};
  (void)hipLaunchCooperativeKernel((const void*)rnn_scan, dim3(NBLK), dim3(512), args, 0, stream);

  copy_hn<<<256, 256, 0, stream>>>(outBase, hnBase);
}